// Round 5
// baseline (446.339 us; speedup 1.0000x reference)
//
#include <hip/hip_runtime.h>
#include <math.h>

#define NUM_ENTS   100000
#define HD         128
#define NUM_EDGES  2000000
#define NUM_RELS2  1000
#define RRELU_SLOPE 0.22916666666666666f
#define NBLK 391                 // ceil(100000/256)
#define NPAD (NBLK * 256)        // 100096 padded counter range
#define EQ4  (NUM_EDGES / 4)     // 500000 4-edge chunks
#define EBLK ((EQ4 + 255) / 256) // 1954 blocks, 1 chunk/thread
#define PBLK ((EQ4 + 511) / 512) // 977 blocks, 2 chunks/thread (permute)

// merged setup_kernel section boundaries (hist FIRST: long-latency atomics
// start earliest and overlap the BW-bound hb/rb/Wp sections)
#define SB_HIST EBLK             // 1954: edge histogram, int4/thread
#define SB_HB   25000            // hb: 25000*4 rows = 100000
#define SB_RB   125              // relpack: 125*256 = 32000 float4 chunks
#define SB_WP   24               // wpack: 24*4 = 96 sub-blocks
#define SB_TOTAL (SB_HIST + SB_HB + SB_RB + SB_WP)   // 27103

typedef __attribute__((ext_vector_type(8))) short bf16x8;
typedef __attribute__((ext_vector_type(4))) float f32x4;
typedef __attribute__((ext_vector_type(2))) float f32x2;
typedef __attribute__((ext_vector_type(2))) unsigned int u32x2;
typedef __attribute__((ext_vector_type(4))) unsigned int u32x4;
typedef __attribute__((ext_vector_type(4))) int i32x4;

// ---------- bf16 helpers ----------
__device__ __forceinline__ float bf2f(unsigned short h) {
    union { unsigned int u; float f; } v;
    v.u = ((unsigned int)h) << 16;
    return v.f;
}
// unpack 2 bf16 (packed in u32) -> f32x2 {lo, hi}
__device__ __forceinline__ f32x2 up2(unsigned int u) {
    union { unsigned int u; float f; } a, b;
    a.u = u << 16;          // low ushort = element c
    b.u = u & 0xffff0000u;  // high ushort = element c+1
    return (f32x2){a.f, b.f};
}
__device__ __forceinline__ unsigned short f2bf(float f) {
    union { float f; unsigned int u; } v; v.f = f;
    unsigned int r = 0x7fffu + ((v.u >> 16) & 1u);  // RNE
    return (unsigned short)((v.u + r) >> 16);
}

// ---------- 1. setup+hist: hist | hb = bf16(l2norm(ent)) | rb | Wp ----------
// cnt is pre-zeroed by hipMemsetAsync before this launch (stream-ordered).
// Atomic returns live HERE (fire -> store pos). R1 lesson: putting the atomic
// return on the permute scatter path costs ~110us of latency stall.
__global__ void __launch_bounds__(256)
setup_kernel(const float* __restrict__ ent, const float* __restrict__ rel,
             const float* __restrict__ Wn, const float* __restrict__ Ws,
             const float* __restrict__ Wt, const int* __restrict__ dst,
             int* __restrict__ cnt, int* __restrict__ pos,
             unsigned short* __restrict__ hb,
             unsigned short* __restrict__ rb, unsigned short* __restrict__ Wp) {
    const int bid = blockIdx.x, tid = threadIdx.x;
    if (bid < SB_HIST) {                                  // hist + pos
        const int i = bid * 256 + tid;
        if (i < EQ4) {
            const i32x4 d4 = ((const i32x4*)dst)[i];      // dst re-read by permute: keep cached
            i32x4 p4;
            p4[0] = atomicAdd(&cnt[d4[0]], 1);
            p4[1] = atomicAdd(&cnt[d4[1]], 1);
            p4[2] = atomicAdd(&cnt[d4[2]], 1);
            p4[3] = atomicAdd(&cnt[d4[3]], 1);
            ((i32x4*)pos)[i] = p4;         // contiguous 16B store
        }
    } else if (bid < SB_HIST + SB_HB) {                   // hb
        const int row = (bid - SB_HIST) * 4 + (tid >> 6);
        const int lane = tid & 63;
        const float2 v = *(const float2*)(ent + (size_t)row * HD + lane * 2);
        float ss = v.x * v.x + v.y * v.y;
        #pragma unroll
        for (int m = 1; m < 64; m <<= 1) ss += __shfl_xor(ss, m, 64);
        const float inv = 1.0f / fmaxf(sqrtf(ss), 1e-12f);
        const unsigned int o = (unsigned int)f2bf(v.x * inv) |
                               ((unsigned int)f2bf(v.y * inv) << 16);
        *(unsigned int*)(hb + (size_t)row * HD + lane * 2) = o;
    } else if (bid < SB_HIST + SB_HB + SB_RB) {           // rb
        const int i = (bid - SB_HIST - SB_HB) * 256 + tid;
        const float4 v = ((const float4*)rel)[i];
        ushort4 o;
        o.x = f2bf(v.x); o.y = f2bf(v.y); o.z = f2bf(v.z); o.w = f2bf(v.w);
        ((ushort4*)rb)[i] = o;
    } else {                                              // Wp
        const int blk = (bid - SB_HIST - SB_HB - SB_RB) * 4 + (tid >> 6);
        const int lane = tid & 63;
        const int w = blk >> 5, rem = blk & 31, t = rem >> 2, kt = rem & 3;
        const float* W = (w == 0) ? Wn : (w == 1) ? Ws : Wt;
        const int n  = t * 16 + (lane & 15);
        const int k0 = kt * 32 + (lane >> 4) * 8;
        unsigned short tmp[8];
        #pragma unroll
        for (int j = 0; j < 8; ++j) tmp[j] = f2bf(W[(size_t)(k0 + j) * HD + n]);
        unsigned short* d = Wp + ((size_t)blk * 64 + lane) * 8;
        *(ushort4*)(d + 0) = make_ushort4(tmp[0], tmp[1], tmp[2], tmp[3]);
        *(ushort4*)(d + 4) = make_ushort4(tmp[4], tmp[5], tmp[6], tmp[7]);
    }
}

// ---------- 2a. scan1: shuffle-based block scan (1 barrier) ----------
// offs[i] = block-local exclusive prefix; bsum[b] = RAW block total (no scan2)
__global__ void __launch_bounds__(256)
scan1_kernel(const int* __restrict__ cnt, int* __restrict__ offs, int* __restrict__ bsum) {
    __shared__ int wsum[4];
    const int t = threadIdx.x, lane = t & 63, wv = t >> 6;
    const int i = blockIdx.x * 256 + t;
    const int v = cnt[i];
    int s = v;                                   // wave-inclusive scan
    #pragma unroll
    for (int d = 1; d < 64; d <<= 1) {
        const int u = __shfl_up(s, d, 64);
        if (lane >= d) s += u;
    }
    if (lane == 63) wsum[wv] = s;
    __syncthreads();
    int p = 0;
    #pragma unroll
    for (int w = 0; w < 3; ++w) p += (w < wv) ? wsum[w] : 0;
    offs[i] = p + s - v;
    if (t == 255) bsum[blockIdx.x] = p + s;      // block total
}

// ---------- 2b. scanB: block b sums bsum[0..b-1], adds to its offs slice ----
// (replaces scan2+scan3: no 1-block serial kernel, one fewer launch)
__global__ void __launch_bounds__(256)
scanB_kernel(int* __restrict__ offs, const int* __restrict__ bsum) {
    __shared__ int red[4];
    const int b = blockIdx.x;
    const int t = threadIdx.x, lane = t & 63, wv = t >> 6;
    int v = 0;
    if (t < b) v = bsum[t];
    if (t + 256 < b) v += bsum[t + 256];
    #pragma unroll
    for (int m = 1; m < 64; m <<= 1) v += __shfl_xor(v, m, 64);
    if (lane == 0) red[wv] = v;
    __syncthreads();
    const int pre = red[0] + red[1] + red[2] + red[3];
    offs[b * 256 + t] += pre;
}

// ---------- 3. permute: pure scatter, NT loads (single-use streams) ----------
__global__ void __launch_bounds__(256)
permute_kernel(const int* __restrict__ dst, const int* __restrict__ src,
               const int* __restrict__ ety, const float* __restrict__ enorm,
               const int* __restrict__ offs, const int* __restrict__ pos,
               u32x2* __restrict__ recs) {
    #pragma unroll
    for (int u = 0; u < 2; ++u) {
        const int i = blockIdx.x * 512 + u * 256 + threadIdx.x;
        if (i < EQ4) {
            const i32x4 d4 = __builtin_nontemporal_load(&((const i32x4*)dst)[i]);
            const i32x4 s4 = __builtin_nontemporal_load(&((const i32x4*)src)[i]);
            const i32x4 t4 = __builtin_nontemporal_load(&((const i32x4*)ety)[i]);
            const f32x4 n4 = __builtin_nontemporal_load(&((const f32x4*)enorm)[i]);
            const i32x4 p4 = __builtin_nontemporal_load(&((const i32x4*)pos)[i]);
            #pragma unroll
            for (int k = 0; k < 4; ++k) {
                u32x2 rc;
                rc[0] = (unsigned int)s4[k] | ((unsigned int)t4[k] << 17);
                union { float f; unsigned int u; } nb; nb.f = n4[k];
                rc[1] = nb.u;
                recs[offs[d4[k]] + p4[k]] = rc;   // normal store: L2 write-combining
            }
        }
    }
}

// ---------- 4. fused gather + MFMA, 16 rows/block ----------
// packed-f32 accumulation: v_pk_add_f32 / v_pk_fma_f32 (3 VALU/elem vs 4)
__device__ __forceinline__ void accum8(f32x2* acc, uint4 hv, uint4 rv, float w) {
    const f32x2 w2 = (f32x2){w, w};
    acc[0] = __builtin_elementwise_fma(up2(hv.x) + up2(rv.x), w2, acc[0]);
    acc[1] = __builtin_elementwise_fma(up2(hv.y) + up2(rv.y), w2, acc[1]);
    acc[2] = __builtin_elementwise_fma(up2(hv.z) + up2(rv.z), w2, acc[2]);
    acc[3] = __builtin_elementwise_fma(up2(hv.w) + up2(rv.w), w2, acc[3]);
}

// Block: 256 threads, 16 rows. Gather: 16 groups x 16 lanes, all dsts in
// parallel; natural per-group loop (group-uniform divergence, no dead loads).
// NT on single-use streams (recs/his/out) protects hb's L2 residency.
// MFMA: 4 waves split the 8 col-tiles (2 each) over one shared LDS tile.
__global__ void __launch_bounds__(256, 4)
gather_mfma(const unsigned short* __restrict__ hb,
            const unsigned short* __restrict__ rb,
            const int* __restrict__ offs,
            const u32x2* __restrict__ recs,
            const unsigned short* __restrict__ Wp,
            const float* __restrict__ bias,
            const float* __restrict__ his,
            float* __restrict__ out) {
    __shared__ unsigned short T[16 * 136];         // 16x128 bf16 tile, pad 8
    const int tid = threadIdx.x;
    const int m0 = blockIdx.x * 16;                // 100000/16 = 6250 exact
    const int grp = tid >> 4, sub = tid & 15;      // gather roles
    const int wv = tid >> 6, lane = tid & 63;
    const int rA = lane & 15, quad = lane >> 4;    // MFMA roles
    const unsigned short* hbp = hb + sub * 8;
    const unsigned short* rbp = rb + sub * 8;

    // ---- gather: one dst per group, 16 dsts fully parallel ----
    {
        const int d = m0 + grp;
        const int beg = offs[d], end = offs[d + 1];
        f32x2 acc[4];
        #pragma unroll
        for (int j = 0; j < 4; ++j) acc[j] = (f32x2)0.f;
        int i = beg;
        if (i < end) {                             // group-uniform divergence
            u32x2 rcA[4];
            #pragma unroll
            for (int k = 0; k < 4; ++k)
                rcA[k] = __builtin_nontemporal_load(&recs[min(i + k, NUM_EDGES - 1)]);
            for (; i < end; i += 4) {
                u32x2 rcB[4];                      // prefetch next iteration's recs
                #pragma unroll
                for (int k = 0; k < 4; ++k)
                    rcB[k] = __builtin_nontemporal_load(&recs[min(i + 4 + k, NUM_EDGES - 1)]);
                uint4 hv[4], rv[4]; float w[4];
                #pragma unroll
                for (int k = 0; k < 4; ++k) {
                    union { unsigned int u; float f; } wb; wb.u = rcA[k][1];
                    w[k] = (i + k) < end ? wb.f : 0.f;
                    hv[k] = *(const uint4*)(hbp + (size_t)(rcA[k][0] & 0x1FFFFu) * HD);
                    rv[k] = *(const uint4*)(rbp + (size_t)(rcA[k][0] >> 17) * HD);
                }
                #pragma unroll
                for (int k = 0; k < 4; ++k) accum8(acc, hv[k], rv[k], w[k]);
                #pragma unroll
                for (int k = 0; k < 4; ++k) rcA[k] = rcB[k];
            }
        }
        unsigned short* dT = T + grp * 136 + sub * 8;
        *(ushort4*)(dT + 0) = make_ushort4(f2bf(acc[0][0]), f2bf(acc[0][1]),
                                           f2bf(acc[1][0]), f2bf(acc[1][1]));
        *(ushort4*)(dT + 4) = make_ushort4(f2bf(acc[2][0]), f2bf(acc[2][1]),
                                           f2bf(acc[3][0]), f2bf(acc[3][1]));
    }
    __syncthreads();

    // ---- MFMA: wave wv owns col-tiles t = wv*2 + tt ----
    const bf16x8* WF = (const bf16x8*)Wp;
    bf16x8 a1[4], a2[4];
    #pragma unroll
    for (int kt = 0; kt < 4; ++kt)
        a1[kt] = *(const bf16x8*)(T + rA * 136 + kt * 32 + quad * 8);
    {
        const unsigned short* base = hb + (size_t)(m0 + rA) * HD + quad * 8;
        #pragma unroll
        for (int kt = 0; kt < 4; ++kt)
            a2[kt] = *(const bf16x8*)(base + kt * 32);
    }

    f32x4 acc1[2];
    #pragma unroll
    for (int tt = 0; tt < 2; ++tt) acc1[tt] = (f32x4)0.f;

    #pragma unroll
    for (int tt = 0; tt < 2; ++tt) {
        const int t = wv * 2 + tt;
        #pragma unroll
        for (int kt = 0; kt < 4; ++kt) {             // phase 1: S @ Wn
            const bf16x8 bfr = WF[(size_t)(t * 4 + kt) * 64 + lane];
            acc1[tt] = __builtin_amdgcn_mfma_f32_16x16x32_bf16(a1[kt], bfr, acc1[tt], 0, 0, 0);
        }
        #pragma unroll
        for (int kt = 0; kt < 4; ++kt) {             // phase 2: h @ Ws
            const bf16x8 bfr = WF[(size_t)(32 + t * 4 + kt) * 64 + lane];
            acc1[tt] = __builtin_amdgcn_mfma_f32_16x16x32_bf16(a2[kt], bfr, acc1[tt], 0, 0, 0);
        }
    }

    // rrelu (C layout: col = t*16 + rA, row = quad*4 + r)
    #pragma unroll
    for (int tt = 0; tt < 2; ++tt)
        #pragma unroll
        for (int r = 0; r < 4; ++r)
            acc1[tt][r] = acc1[tt][r] >= 0.f ? acc1[tt][r] : RRELU_SLOPE * acc1[tt][r];

    __syncthreads();                                 // all a1 reads of T done
    // transpose hcur C-layout -> A-layout into T (each wave its 32 cols)
    #pragma unroll
    for (int tt = 0; tt < 2; ++tt)
        #pragma unroll
        for (int r = 0; r < 4; ++r)
            T[(quad * 4 + r) * 136 + (wv * 2 + tt) * 16 + rA] = f2bf(acc1[tt][r]);
    __syncthreads();

    bf16x8 a3[4];
    #pragma unroll
    for (int kt = 0; kt < 4; ++kt)
        a3[kt] = *(const bf16x8*)(T + rA * 136 + kt * 32 + quad * 8);

    // phase 3 + epilogue per col-tile
    #pragma unroll
    for (int tt = 0; tt < 2; ++tt) {
        const int t = wv * 2 + tt;
        const float bn = bias[t * 16 + rA];
        f32x4 c2 = (f32x4){bn, bn, bn, bn};
        #pragma unroll
        for (int kt = 0; kt < 4; ++kt) {
            const bf16x8 bfr = WF[(size_t)(64 + t * 4 + kt) * 64 + lane];
            c2 = __builtin_amdgcn_mfma_f32_16x16x32_bf16(a3[kt], bfr, c2, 0, 0, 0);
        }
        const int col = t * 16 + rA;
        #pragma unroll
        for (int r = 0; r < 4; ++r) {
            const size_t row = (size_t)(m0 + quad * 4 + r);
            const float g = 1.f / (1.f + __expf(-c2[r]));
            const float h = __builtin_nontemporal_load(his + row * HD + col);
            __builtin_nontemporal_store(g * acc1[tt][r] + (1.f - g) * h,
                                        out + row * HD + col);
        }
    }
}

// ---------- launch ----------
extern "C" void kernel_launch(void* const* d_in, const int* in_sizes, int n_in,
                              void* d_out, int out_size, void* d_ws, size_t ws_size,
                              hipStream_t stream) {
    const float* ent   = (const float*)d_in[0];
    const float* rel   = (const float*)d_in[1];
    const float* his   = (const float*)d_in[2];
    const float* Wn    = (const float*)d_in[3];
    const float* Ws    = (const float*)d_in[4];
    const float* Wt    = (const float*)d_in[5];
    const float* bias  = (const float*)d_in[6];
    const float* enorm = (const float*)d_in[7];
    const int* src = (const int*)d_in[8];
    const int* dst = (const int*)d_in[9];
    const int* ety = (const int*)d_in[10];
    float* out = (float*)d_out;

    // ws: hb 25.6MB | rb 256KB | Wp 96KB | cnt 400KB | offs 400KB | bsum 2KB |
    //     pos 8MB | recs 16MB   (~50.8MB; ws >= 51.6MB)
    char* p = (char*)d_ws;
    unsigned short* hb = (unsigned short*)p;  p += (size_t)NUM_ENTS * HD * 2;
    unsigned short* rb = (unsigned short*)p;  p += (size_t)NUM_RELS2 * HD * 2;
    unsigned short* Wp = (unsigned short*)p;  p += (size_t)96 * 64 * 8 * 2;
    int* cnt  = (int*)p;                      p += (size_t)NPAD * 4;
    int* offs = (int*)p;                      p += (size_t)NPAD * 4;
    int* bsum = (int*)p;                      p += 512 * 4;
    int* pos  = (int*)p;                      p += (size_t)NUM_EDGES * 4;
    u32x2* recs = (u32x2*)p;

    hipMemsetAsync(cnt, 0, (size_t)NPAD * 4, stream);   // async, capture-safe
    setup_kernel<<<SB_TOTAL, 256, 0, stream>>>(ent, rel, Wn, Ws, Wt, dst, cnt, pos, hb, rb, Wp);
    scan1_kernel<<<NBLK, 256, 0, stream>>>(cnt, offs, bsum);
    scanB_kernel<<<NBLK, 256, 0, stream>>>(offs, bsum);
    permute_kernel<<<PBLK, 256, 0, stream>>>(dst, src, ety, enorm, offs, pos, recs);
    gather_mfma<<<NUM_ENTS / 16, 256, 0, stream>>>(hb, rb, offs, recs, Wp, bias, his, out);
}

// Round 6
// 411.399 us; speedup vs baseline: 1.0849x; 1.0849x over previous
//
#include <hip/hip_runtime.h>
#include <math.h>

#define NUM_ENTS   100000
#define HD         128
#define NUM_EDGES  2000000
#define NUM_RELS2  1000
#define RRELU_SLOPE 0.22916666666666666f
#define NBLK 391                 // ceil(100000/256)
#define NPAD (NBLK * 256)        // 100096 padded counter range
#define EQ4  (NUM_EDGES / 4)     // 500000 4-edge chunks
#define EBLK ((EQ4 + 255) / 256) // 1954 blocks, 1 chunk/thread
#define PBLK ((EQ4 + 511) / 512) // 977 blocks, 2 chunks/thread (permute)

// merged setup_kernel section boundaries (hist FIRST: long-latency atomics
// start earliest and overlap the BW-bound hb/rb/Wp sections)
#define SB_HIST EBLK             // 1954: edge histogram, int4/thread
#define SB_HB   25000            // hb: 25000*4 rows = 100000
#define SB_RB   125              // relpack: 125*256 = 32000 float4 chunks
#define SB_WP   24               // wpack: 24*4 = 96 sub-blocks
#define SB_TOTAL (SB_HIST + SB_HB + SB_RB + SB_WP)   // 27103

typedef __attribute__((ext_vector_type(8))) short bf16x8;
typedef __attribute__((ext_vector_type(4))) float f32x4;
typedef __attribute__((ext_vector_type(2))) float f32x2;
typedef __attribute__((ext_vector_type(2))) unsigned int u32x2;
typedef __attribute__((ext_vector_type(4))) int i32x4;

// ---------- bf16 helpers ----------
__device__ __forceinline__ float bf2f(unsigned short h) {
    union { unsigned int u; float f; } v;
    v.u = ((unsigned int)h) << 16;
    return v.f;
}
// unpack 2 bf16 (packed in u32) -> f32x2 {lo, hi}
__device__ __forceinline__ f32x2 up2(unsigned int u) {
    union { unsigned int u; float f; } a, b;
    a.u = u << 16;          // low ushort = element c
    b.u = u & 0xffff0000u;  // high ushort = element c+1
    return (f32x2){a.f, b.f};
}
__device__ __forceinline__ unsigned short f2bf(float f) {
    union { float f; unsigned int u; } v; v.f = f;
    unsigned int r = 0x7fffu + ((v.u >> 16) & 1u);  // RNE
    return (unsigned short)((v.u + r) >> 16);
}

// ---------- 1. setup+hist: hist | hb = bf16(l2norm(ent)) | rb | Wp ----------
// cnt is pre-zeroed by hipMemsetAsync before this launch (stream-ordered).
// Atomic returns live HERE (fire -> store pos). R1 lesson: putting the atomic
// return on the permute scatter path costs ~110us of latency stall.
__global__ void __launch_bounds__(256)
setup_kernel(const float* __restrict__ ent, const float* __restrict__ rel,
             const float* __restrict__ Wn, const float* __restrict__ Ws,
             const float* __restrict__ Wt, const int* __restrict__ dst,
             int* __restrict__ cnt, int* __restrict__ pos,
             unsigned short* __restrict__ hb,
             unsigned short* __restrict__ rb, unsigned short* __restrict__ Wp) {
    const int bid = blockIdx.x, tid = threadIdx.x;
    if (bid < SB_HIST) {                                  // hist + pos
        const int i = bid * 256 + tid;
        if (i < EQ4) {
            const i32x4 d4 = ((const i32x4*)dst)[i];
            i32x4 p4;
            p4[0] = atomicAdd(&cnt[d4[0]], 1);
            p4[1] = atomicAdd(&cnt[d4[1]], 1);
            p4[2] = atomicAdd(&cnt[d4[2]], 1);
            p4[3] = atomicAdd(&cnt[d4[3]], 1);
            ((i32x4*)pos)[i] = p4;         // contiguous 16B store
        }
    } else if (bid < SB_HIST + SB_HB) {                   // hb
        const int row = (bid - SB_HIST) * 4 + (tid >> 6);
        const int lane = tid & 63;
        const float2 v = *(const float2*)(ent + (size_t)row * HD + lane * 2);
        float ss = v.x * v.x + v.y * v.y;
        #pragma unroll
        for (int m = 1; m < 64; m <<= 1) ss += __shfl_xor(ss, m, 64);
        const float inv = 1.0f / fmaxf(sqrtf(ss), 1e-12f);
        const unsigned int o = (unsigned int)f2bf(v.x * inv) |
                               ((unsigned int)f2bf(v.y * inv) << 16);
        *(unsigned int*)(hb + (size_t)row * HD + lane * 2) = o;
    } else if (bid < SB_HIST + SB_HB + SB_RB) {           // rb
        const int i = (bid - SB_HIST - SB_HB) * 256 + tid;
        const float4 v = ((const float4*)rel)[i];
        ushort4 o;
        o.x = f2bf(v.x); o.y = f2bf(v.y); o.z = f2bf(v.z); o.w = f2bf(v.w);
        ((ushort4*)rb)[i] = o;
    } else {                                              // Wp
        const int blk = (bid - SB_HIST - SB_HB - SB_RB) * 4 + (tid >> 6);
        const int lane = tid & 63;
        const int w = blk >> 5, rem = blk & 31, t = rem >> 2, kt = rem & 3;
        const float* W = (w == 0) ? Wn : (w == 1) ? Ws : Wt;
        const int n  = t * 16 + (lane & 15);
        const int k0 = kt * 32 + (lane >> 4) * 8;
        unsigned short tmp[8];
        #pragma unroll
        for (int j = 0; j < 8; ++j) tmp[j] = f2bf(W[(size_t)(k0 + j) * HD + n]);
        unsigned short* d = Wp + ((size_t)blk * 64 + lane) * 8;
        *(ushort4*)(d + 0) = make_ushort4(tmp[0], tmp[1], tmp[2], tmp[3]);
        *(ushort4*)(d + 4) = make_ushort4(tmp[4], tmp[5], tmp[6], tmp[7]);
    }
}

// ---------- 2a. scan1: shuffle-based block scan (1 barrier) ----------
// offs[i] = block-local exclusive prefix; bsum[b] = RAW block total
__global__ void __launch_bounds__(256)
scan1_kernel(const int* __restrict__ cnt, int* __restrict__ offs, int* __restrict__ bsum) {
    __shared__ int wsum[4];
    const int t = threadIdx.x, lane = t & 63, wv = t >> 6;
    const int i = blockIdx.x * 256 + t;
    const int v = cnt[i];
    int s = v;                                   // wave-inclusive scan
    #pragma unroll
    for (int d = 1; d < 64; d <<= 1) {
        const int u = __shfl_up(s, d, 64);
        if (lane >= d) s += u;
    }
    if (lane == 63) wsum[wv] = s;
    __syncthreads();
    int p = 0;
    #pragma unroll
    for (int w = 0; w < 3; ++w) p += (w < wv) ? wsum[w] : 0;
    offs[i] = p + s - v;
    if (t == 255) bsum[blockIdx.x] = p + s;      // block total
}

// ---------- 2b. scanB: block b sums bsum[0..b-1], adds to its offs slice ----
// (replaces scan2+scan3: no 1-block serial kernel, one fewer launch)
__global__ void __launch_bounds__(256)
scanB_kernel(int* __restrict__ offs, const int* __restrict__ bsum) {
    __shared__ int red[4];
    const int b = blockIdx.x;
    const int t = threadIdx.x, lane = t & 63, wv = t >> 6;
    int v = 0;
    if (t < b) v = bsum[t];
    if (t + 256 < b) v += bsum[t + 256];
    #pragma unroll
    for (int m = 1; m < 64; m <<= 1) v += __shfl_xor(v, m, 64);
    if (lane == 0) red[wv] = v;
    __syncthreads();
    const int pre = red[0] + red[1] + red[2] + red[3];
    offs[b * 256 + t] += pre;
}

// ---------- 3. permute: pure scatter, plain loads only (no atomics) ----------
// R5 lesson: NO nontemporal hints anywhere — NT broke L2 write-combining on
// scattered stores (+7MB WRITE) and L1/L2 reuse on loads (+66MB FETCH).
__global__ void __launch_bounds__(256)
permute_kernel(const int* __restrict__ dst, const int* __restrict__ src,
               const int* __restrict__ ety, const float* __restrict__ enorm,
               const int* __restrict__ offs, const int* __restrict__ pos,
               u32x2* __restrict__ recs) {
    #pragma unroll
    for (int u = 0; u < 2; ++u) {
        const int i = blockIdx.x * 512 + u * 256 + threadIdx.x;
        if (i < EQ4) {
            const i32x4 d4 = ((const i32x4*)dst)[i];
            const i32x4 s4 = ((const i32x4*)src)[i];
            const i32x4 t4 = ((const i32x4*)ety)[i];
            const f32x4 n4 = ((const f32x4*)enorm)[i];
            const i32x4 p4 = ((const i32x4*)pos)[i];
            #pragma unroll
            for (int k = 0; k < 4; ++k) {
                u32x2 rc;
                rc[0] = (unsigned int)s4[k] | ((unsigned int)t4[k] << 17);
                union { float f; unsigned int u; } nb; nb.f = n4[k];
                rc[1] = nb.u;
                recs[offs[d4[k]] + p4[k]] = rc;
            }
        }
    }
}

// ---------- 4. fused gather + MFMA, 16 rows/block ----------
// packed-f32 accumulation: v_pk_add_f32 / v_pk_fma_f32 (3 VALU/elem vs 4)
__device__ __forceinline__ void accum8(f32x2* acc, uint4 hv, uint4 rv, float w) {
    const f32x2 w2 = (f32x2){w, w};
    acc[0] = __builtin_elementwise_fma(up2(hv.x) + up2(rv.x), w2, acc[0]);
    acc[1] = __builtin_elementwise_fma(up2(hv.y) + up2(rv.y), w2, acc[1]);
    acc[2] = __builtin_elementwise_fma(up2(hv.z) + up2(rv.z), w2, acc[2]);
    acc[3] = __builtin_elementwise_fma(up2(hv.w) + up2(rv.w), w2, acc[3]);
}

// Block: 256 threads, 16 rows. Gather: 16 groups x 16 lanes, all dsts in
// parallel; natural per-group loop (group-uniform divergence, no dead loads).
// MFMA: 4 waves split the 8 col-tiles (2 each) over one shared LDS tile.
__global__ void __launch_bounds__(256, 4)
gather_mfma(const unsigned short* __restrict__ hb,
            const unsigned short* __restrict__ rb,
            const int* __restrict__ offs,
            const u32x2* __restrict__ recs,
            const unsigned short* __restrict__ Wp,
            const float* __restrict__ bias,
            const float* __restrict__ his,
            float* __restrict__ out) {
    __shared__ unsigned short T[16 * 136];         // 16x128 bf16 tile, pad 8
    const int tid = threadIdx.x;
    const int m0 = blockIdx.x * 16;                // 100000/16 = 6250 exact
    const int grp = tid >> 4, sub = tid & 15;      // gather roles
    const int wv = tid >> 6, lane = tid & 63;
    const int rA = lane & 15, quad = lane >> 4;    // MFMA roles
    const unsigned short* hbp = hb + sub * 8;
    const unsigned short* rbp = rb + sub * 8;

    // ---- gather: one dst per group, 16 dsts fully parallel ----
    {
        const int d = m0 + grp;
        const int beg = offs[d], end = offs[d + 1];
        f32x2 acc[4];
        #pragma unroll
        for (int j = 0; j < 4; ++j) acc[j] = (f32x2)0.f;
        int i = beg;
        if (i < end) {                             // group-uniform divergence
            u32x2 rcA[4];
            #pragma unroll
            for (int k = 0; k < 4; ++k) rcA[k] = recs[min(i + k, NUM_EDGES - 1)];
            for (; i < end; i += 4) {
                u32x2 rcB[4];                      // prefetch next iteration's recs
                #pragma unroll
                for (int k = 0; k < 4; ++k) rcB[k] = recs[min(i + 4 + k, NUM_EDGES - 1)];
                uint4 hv[4], rv[4]; float w[4];
                #pragma unroll
                for (int k = 0; k < 4; ++k) {
                    union { unsigned int u; float f; } wb; wb.u = rcA[k][1];
                    w[k] = (i + k) < end ? wb.f : 0.f;
                    hv[k] = *(const uint4*)(hbp + (size_t)(rcA[k][0] & 0x1FFFFu) * HD);
                    rv[k] = *(const uint4*)(rbp + (size_t)(rcA[k][0] >> 17) * HD);
                }
                #pragma unroll
                for (int k = 0; k < 4; ++k) accum8(acc, hv[k], rv[k], w[k]);
                #pragma unroll
                for (int k = 0; k < 4; ++k) rcA[k] = rcB[k];
            }
        }
        unsigned short* dT = T + grp * 136 + sub * 8;
        *(ushort4*)(dT + 0) = make_ushort4(f2bf(acc[0][0]), f2bf(acc[0][1]),
                                           f2bf(acc[1][0]), f2bf(acc[1][1]));
        *(ushort4*)(dT + 4) = make_ushort4(f2bf(acc[2][0]), f2bf(acc[2][1]),
                                           f2bf(acc[3][0]), f2bf(acc[3][1]));
    }
    __syncthreads();

    // ---- MFMA: wave wv owns col-tiles t = wv*2 + tt ----
    const bf16x8* WF = (const bf16x8*)Wp;
    bf16x8 a1[4], a2[4];
    #pragma unroll
    for (int kt = 0; kt < 4; ++kt)
        a1[kt] = *(const bf16x8*)(T + rA * 136 + kt * 32 + quad * 8);
    {
        const unsigned short* base = hb + (size_t)(m0 + rA) * HD + quad * 8;
        #pragma unroll
        for (int kt = 0; kt < 4; ++kt)
            a2[kt] = *(const bf16x8*)(base + kt * 32);
    }

    f32x4 acc1[2];
    #pragma unroll
    for (int tt = 0; tt < 2; ++tt) acc1[tt] = (f32x4)0.f;

    #pragma unroll
    for (int tt = 0; tt < 2; ++tt) {
        const int t = wv * 2 + tt;
        #pragma unroll
        for (int kt = 0; kt < 4; ++kt) {             // phase 1: S @ Wn
            const bf16x8 bfr = WF[(size_t)(t * 4 + kt) * 64 + lane];
            acc1[tt] = __builtin_amdgcn_mfma_f32_16x16x32_bf16(a1[kt], bfr, acc1[tt], 0, 0, 0);
        }
        #pragma unroll
        for (int kt = 0; kt < 4; ++kt) {             // phase 2: h @ Ws
            const bf16x8 bfr = WF[(size_t)(32 + t * 4 + kt) * 64 + lane];
            acc1[tt] = __builtin_amdgcn_mfma_f32_16x16x32_bf16(a2[kt], bfr, acc1[tt], 0, 0, 0);
        }
    }

    // rrelu (C layout: col = t*16 + rA, row = quad*4 + r)
    #pragma unroll
    for (int tt = 0; tt < 2; ++tt)
        #pragma unroll
        for (int r = 0; r < 4; ++r)
            acc1[tt][r] = acc1[tt][r] >= 0.f ? acc1[tt][r] : RRELU_SLOPE * acc1[tt][r];

    __syncthreads();                                 // all a1 reads of T done
    // transpose hcur C-layout -> A-layout into T (each wave its 32 cols)
    #pragma unroll
    for (int tt = 0; tt < 2; ++tt)
        #pragma unroll
        for (int r = 0; r < 4; ++r)
            T[(quad * 4 + r) * 136 + (wv * 2 + tt) * 16 + rA] = f2bf(acc1[tt][r]);
    __syncthreads();

    bf16x8 a3[4];
    #pragma unroll
    for (int kt = 0; kt < 4; ++kt)
        a3[kt] = *(const bf16x8*)(T + rA * 136 + kt * 32 + quad * 8);

    // phase 3 + epilogue per col-tile
    #pragma unroll
    for (int tt = 0; tt < 2; ++tt) {
        const int t = wv * 2 + tt;
        const float bn = bias[t * 16 + rA];
        f32x4 c2 = (f32x4){bn, bn, bn, bn};
        #pragma unroll
        for (int kt = 0; kt < 4; ++kt) {
            const bf16x8 bfr = WF[(size_t)(64 + t * 4 + kt) * 64 + lane];
            c2 = __builtin_amdgcn_mfma_f32_16x16x32_bf16(a3[kt], bfr, c2, 0, 0, 0);
        }
        const int col = t * 16 + rA;
        #pragma unroll
        for (int r = 0; r < 4; ++r) {
            const size_t row = (size_t)(m0 + quad * 4 + r);
            const float g = 1.f / (1.f + __expf(-c2[r]));
            const float h = his[row * HD + col];
            out[row * HD + col] = g * acc1[tt][r] + (1.f - g) * h;
        }
    }
}

// ---------- launch ----------
extern "C" void kernel_launch(void* const* d_in, const int* in_sizes, int n_in,
                              void* d_out, int out_size, void* d_ws, size_t ws_size,
                              hipStream_t stream) {
    const float* ent   = (const float*)d_in[0];
    const float* rel   = (const float*)d_in[1];
    const float* his   = (const float*)d_in[2];
    const float* Wn    = (const float*)d_in[3];
    const float* Ws    = (const float*)d_in[4];
    const float* Wt    = (const float*)d_in[5];
    const float* bias  = (const float*)d_in[6];
    const float* enorm = (const float*)d_in[7];
    const int* src = (const int*)d_in[8];
    const int* dst = (const int*)d_in[9];
    const int* ety = (const int*)d_in[10];
    float* out = (float*)d_out;

    // ws: hb 25.6MB | rb 256KB | Wp 96KB | cnt 400KB | offs 400KB | bsum 2KB |
    //     pos 8MB | recs 16MB   (~50.8MB; ws >= 51.6MB)
    char* p = (char*)d_ws;
    unsigned short* hb = (unsigned short*)p;  p += (size_t)NUM_ENTS * HD * 2;
    unsigned short* rb = (unsigned short*)p;  p += (size_t)NUM_RELS2 * HD * 2;
    unsigned short* Wp = (unsigned short*)p;  p += (size_t)96 * 64 * 8 * 2;
    int* cnt  = (int*)p;                      p += (size_t)NPAD * 4;
    int* offs = (int*)p;                      p += (size_t)NPAD * 4;
    int* bsum = (int*)p;                      p += 512 * 4;
    int* pos  = (int*)p;                      p += (size_t)NUM_EDGES * 4;
    u32x2* recs = (u32x2*)p;

    hipMemsetAsync(cnt, 0, (size_t)NPAD * 4, stream);   // async, capture-safe
    setup_kernel<<<SB_TOTAL, 256, 0, stream>>>(ent, rel, Wn, Ws, Wt, dst, cnt, pos, hb, rb, Wp);
    scan1_kernel<<<NBLK, 256, 0, stream>>>(cnt, offs, bsum);
    scanB_kernel<<<NBLK, 256, 0, stream>>>(offs, bsum);
    permute_kernel<<<PBLK, 256, 0, stream>>>(dst, src, ety, enorm, offs, pos, recs);
    gather_mfma<<<NUM_ENTS / 16, 256, 0, stream>>>(hb, rb, offs, recs, Wp, bias, his, out);
}